// Round 2
// 58.886 us; speedup vs baseline: 1.0161x; 1.0161x over previous
//
#include <hip/hip_runtime.h>
#include <math.h>

// STDP_84791244358141 — T=256, N=1024, AP=AN=1, TP=TN=2, TE=1. fp32 in/out.
//
// MATH (verified r5/r6, absmax 0.0 vs np ref): te=1 makes the e-carry dead;
//     e[i][j] = x_T[i]*q_T[j] - p_T[i]*y_T[j]
// with x_t = x + (p - x)/2 and p_T/q_T the last spike rows.
//
// R7: rocprof shows the timed region is dominated by the harness's 256 MiB
// workspace poison fill (~41 us @ 81% HBM peak). Our controllable slice was
// ~18.8 us across TWO kernels whose actual execution is ~3 us — i.e. mostly
// launch/serialization overhead. Fix: fuse traces+outer into ONE kernel.
// Each 64x64 output tile recomputes the 128 trace columns it needs
// (4 segments x 128 cols = 512 threads; exact power-of-2 ldexpf recombine,
// same verified scheme as r6). Redundant reads = 32 MiB, all L2-resident
// (source is 2 MiB). No workspace, no inter-kernel dependency.
//
// R8: round-1 bench was an infra failure (container acquisition), not a
// kernel failure — resubmitting unchanged.

constexpr int BLOCK = 256;   // fallback kernels

// ---------------------------------------------------------------------------
// Fused kernel: grid = (Npre/64)*(Npost/64) blocks, 512 threads.
// Requires T % 64 == 0, Npre % 64 == 0, Npost % 64 == 0.
// Thread map (trace phase): c = tid&127 (0..63 pre-col, 64..127 post-col),
// seg = tid>>7 (4 time segments of L = T/4). 16 batched loads per drain.
// Segment partials combine exactly: v = sum_s w_s * 2^(-L*(3-s)) (ldexpf;
// underflow->0 matches true decay). Reassociation error ~1 ulp << 2% thresh.
// ---------------------------------------------------------------------------
__global__ __launch_bounds__(512) void stdp_fused(
    const float* __restrict__ pre, const float* __restrict__ post,
    float* __restrict__ out, int Npre, int Npost, int T)
{
    const int nbj = Npost >> 6;                // tiles along post/cols
    const int bi  = blockIdx.x / nbj;
    const int bj  = blockIdx.x - bi * nbj;

    const int tid = threadIdx.x;
    const int c   = tid & 127;                 // trace column within block
    const int seg = tid >> 7;                  // 0..3
    const bool isPost = (c >= 64);
    const int lc  = c & 63;
    const int gcol   = ((isPost ? bj : bi) << 6) + lc;
    const float* __restrict__ src = isPost ? post : pre;
    const int stride = isPost ? Npost : Npre;

    const int L  = T >> 2;                     // 64 for T=256
    const int t0 = seg * L;

    float v = 0.0f, last = 0.0f;
    for (int tb = 0; tb < L; tb += 16) {
        float tmp[16];
#pragma unroll
        for (int k = 0; k < 16; ++k)           // 16 independent loads, 1 drain
            tmp[k] = src[(size_t)(t0 + tb + k) * stride + gcol];
#pragma unroll
        for (int k = 0; k < 16; ++k)
            v += (tmp[k] - v) * 0.5f;          // reference rounding sequence
        last = tmp[15];
    }

    __shared__ float part[512];
    __shared__ float xs[64], ps[64], ys[64], qs[64];
    part[tid] = ldexpf(v, -L * (3 - seg));     // exact pow2 scale; uflow -> 0
    if (seg == 3)
        (isPost ? qs : ps)[lc] = last;         // p_T / q_T (t = T-1 row)
    __syncthreads();
    if (tid < 128) {
        // ascending segment = ascending magnitude
        float s = ((part[tid] + part[128 + tid]) + part[256 + tid])
                  + part[384 + tid];
        (tid < 64 ? xs : ys)[tid & 63] = s;
    }
    __syncthreads();

    // Outer product: 64x64 tile = 1024 float4 groups, 2 per thread.
    const size_t obase = ((size_t)(bi << 6)) * Npost + (size_t)(bj << 6);
#pragma unroll
    for (int g = tid; g < 1024; g += 512) {
        const int row = g >> 4;                // 16 float4 per 64-col row
        const int cg  = (g & 15) << 2;
        const float x_i = xs[row], p_i = ps[row];
        float4 o;
        o.x = x_i * qs[cg + 0] - p_i * ys[cg + 0];
        o.y = x_i * qs[cg + 1] - p_i * ys[cg + 1];
        o.z = x_i * qs[cg + 2] - p_i * ys[cg + 2];
        o.w = x_i * qs[cg + 3] - p_i * ys[cg + 3];
        *reinterpret_cast<float4*>(out + obase + (size_t)row * Npost + cg) = o;
    }
}

// ---------------------------------------------------------------------------
// Generic fallback (any T, Npre, Npost): sequential trace scan + outer.
// ws layout: traces x[Npre],y[Npost] at [0, Np+Nq); lasts p,q at [Np+Nq, 2(..)).
// ---------------------------------------------------------------------------
__global__ __launch_bounds__(BLOCK) void stdp_traces_gen(
    const float* __restrict__ pre, const float* __restrict__ post,
    float* __restrict__ ws, int Npre, int Npost, int T)
{
    const int gid = blockIdx.x * BLOCK + threadIdx.x;
    if (gid >= Npre + Npost) return;
    const bool isPost = gid >= Npre;
    const float* __restrict__ src = isPost ? post : pre;
    const int stride = isPost ? Npost : Npre;
    const int cIdx   = isPost ? gid - Npre : gid;
    float v = 0.0f, last = 0.0f;
    for (int t = 0; t < T; ++t) {
        const float s = src[(size_t)t * stride + cIdx];
        v += (s - v) * 0.5f;
        last = s;
    }
    ws[gid] = v;
    ws[Npre + Npost + gid] = last;
}

__global__ __launch_bounds__(BLOCK) void stdp_outer_gen(
    const float* __restrict__ ws, float* __restrict__ out, int Npre, int Npost)
{
    const int i = blockIdx.x;
    const float x_i = ws[i];
    const float p_i = ws[Npre + Npost + i];
    const float* __restrict__ ys = ws + Npre;
    const float* __restrict__ qs = ws + 2 * Npre + Npost;
    if ((Npost & 3) == 0) {
        for (int j0 = threadIdx.x * 4; j0 < Npost; j0 += BLOCK * 4) {
            const float4 y4 = *reinterpret_cast<const float4*>(ys + j0);
            const float4 q4 = *reinterpret_cast<const float4*>(qs + j0);
            float4 o;
            o.x = x_i * q4.x - p_i * y4.x;
            o.y = x_i * q4.y - p_i * y4.y;
            o.z = x_i * q4.z - p_i * y4.z;
            o.w = x_i * q4.w - p_i * y4.w;
            *reinterpret_cast<float4*>(out + (size_t)i * Npost + j0) = o;
        }
    } else {
        for (int j = threadIdx.x; j < Npost; j += BLOCK)
            out[(size_t)i * Npost + j] = x_i * qs[j] - p_i * ys[j];
    }
}

extern "C" void kernel_launch(void* const* d_in, const int* in_sizes, int n_in,
                              void* d_out, int out_size, void* d_ws, size_t ws_size,
                              hipStream_t stream)
{
    // in0 = T*N_pre, in1 = T*N_post, out = N_pre*N_post => T = sqrt(in0*in1/out)
    const double t_d = sqrt((double)in_sizes[0] * (double)in_sizes[1] / (double)out_size);
    const int T     = (int)(t_d + 0.5);
    const int Npre  = in_sizes[0] / T;
    const int Npost = in_sizes[1] / T;

    const float* pre  = (const float*)d_in[0];
    const float* post = (const float*)d_in[1];
    float* out = (float*)d_out;
    float* ws  = (float*)d_ws;                 // fallback path only: 2*(Np+Nq) floats

    if (T % 64 == 0 && Npre % 64 == 0 && Npost % 64 == 0) {
        const int grid = (Npre >> 6) * (Npost >> 6);
        stdp_fused<<<grid, 512, 0, stream>>>(pre, post, out, Npre, Npost, T);
    } else {
        stdp_traces_gen<<<(Npre + Npost + BLOCK - 1) / BLOCK, BLOCK, 0, stream>>>(
            pre, post, ws, Npre, Npost, T);
        stdp_outer_gen<<<Npre, BLOCK, 0, stream>>>(ws, out, Npre, Npost);
    }
}